// Round 23
// baseline (86.285 us; speedup 1.0000x reference)
//
#include <hip/hip_runtime.h>
#include <hip/hip_fp8.h>

// NewSupConLoss: B=512, L=20, D=128. Full Gram N=10240, fused exp/rowsum.
// Round 23: R19 geometry (fp8, 6400 single-wave units, 64 rows x 256 cols,
// 16-col slices) but ZERO LDS: B fragments load directly from linear f8
// into a static two-buffer register pipeline (b0/b1), bypassing the
// global_load_lds DMA path that has pinned staging at ~35 GB/s/CU across
// every prior config. L1 absorbs the 4x reuse within each slice.

#define NB 512
#define NL 20
#define NROW (NB * NL)            // 10240
#define F8BYTES (NROW * 128)      // 1,310,720
#define SCALE 4.5398160f          // sqrt(log2(e)/0.07); dot feeds exp2 directly
#define TEMP_INV 14.285714285714286f

typedef float f32x4 __attribute__((ext_vector_type(4)));

static __device__ __forceinline__ unsigned char f2fp8(float x) {
  __hip_fp8_e4m3 q(x);
  return (unsigned char)q.__x;
}

static __device__ __forceinline__ float fexp2(float x) {
#if __has_builtin(__builtin_amdgcn_exp2f)
  return __builtin_amdgcn_exp2f(x);
#else
  return exp2f(x);
#endif
}

// Blocks [0,640): fp32 -> fp8 rows a=l*512+i, scaled, LINEAR layout.
// Blocks [640,960): gp[c][grp][d] partial g-sums (16 independent loads).
__global__ __launch_bounds__(256) void k_prep(const float* __restrict__ feat,
                                              const int* __restrict__ labels,
                                              unsigned char* __restrict__ f8,
                                              float* __restrict__ gp) {
  const int b = blockIdx.x;
  if (b < 640) {
    int t = b * 256 + threadIdx.x;   // [0, 163840)
    int q = t & 15;                  // 8-elem chunk within row
    int a = t >> 4;                  // row 0..10239
    int l = a >> 9;
    int i = a & 511;
    const float* src = feat + (size_t)i * (NL * 128) + l * 128 + q * 8;
    float4 v0 = *(const float4*)src;
    float4 v1 = *(const float4*)(src + 4);
    unsigned long long u = 0;
    u |= (unsigned long long)f2fp8(v0.x * SCALE);
    u |= (unsigned long long)f2fp8(v0.y * SCALE) << 8;
    u |= (unsigned long long)f2fp8(v0.z * SCALE) << 16;
    u |= (unsigned long long)f2fp8(v0.w * SCALE) << 24;
    u |= (unsigned long long)f2fp8(v1.x * SCALE) << 32;
    u |= (unsigned long long)f2fp8(v1.y * SCALE) << 40;
    u |= (unsigned long long)f2fp8(v1.z * SCALE) << 48;
    u |= (unsigned long long)f2fp8(v1.w * SCALE) << 56;
    *(unsigned long long*)(f8 + (size_t)a * 128 + q * 8) = u;
  } else {
    __shared__ float part[2][128];
    const int idx = b - 640;           // [0,320)
    const int c = idx >> 4, grp = idx & 15;
    const int d = threadIdx.x & 127, half = threadIdx.x >> 7;
    const int i0 = grp * 32 + half * 16;
    float s = 0.f;
#pragma unroll
    for (int k = 0; k < 16; ++k) {     // independent load pairs, latency-hidden
      int i = i0 + k;
      s += (float)labels[i * NL + c] * feat[(size_t)i * (NL * 128) + c * 128 + d];
    }
    part[half][d] = s;
    __syncthreads();
    if (half == 0) gp[(c * 16 + grp) * 128 + d] = part[0][d] + part[1][d];
  }
}

// Pr[c][h][sr][r] : partial row-sums of exp over 256 cols (class c, half h).
// Grid (320 = sr*2+h, 20 c), 64 threads (1 wave), NO LDS.
__global__ __launch_bounds__(64) void k_gram(const unsigned char* __restrict__ f8,
                                             float* __restrict__ Pr) {
  const int x = blockIdx.x;              // [0,320)
  const int h = x & 1, sr = x >> 1;      // col half, 64-row strip [sr*64,+64)
  const int c = blockIdx.y;              // class: cols [c*512 + h*256, +256)
  const int lane = threadIdx.x;          // 0..63
  const int fr = lane & 15, kg = lane >> 4;

  // ---- persistent A fragments: 16 x long = 32 VGPR ----
  long af[4][4];   // [kk][m]
#pragma unroll
  for (int kk = 0; kk < 4; ++kk)
#pragma unroll
    for (int m = 0; m < 4; ++m)
      af[kk][m] = *(const long*)(f8 + (size_t)(sr * 64 + m * 16 + fr) * 128 +
                                 kk * 32 + kg * 8);

  // per-lane B base: slice t adds t*16*128 bytes; lane reads row fr, chunk kg
  const unsigned char* gL = f8 + ((size_t)(c * 512 + h * 256) + fr) * 128 + kg * 8;

  long b0[4], b1[4];
#define LOADB(DST, T)                                                        \
  {                                                                          \
    const unsigned char* g_ = gL + (size_t)(T) * 2048;                       \
    _Pragma("unroll") for (int kk_ = 0; kk_ < 4; ++kk_)                      \
        DST[kk_] = *(const long*)(g_ + kk_ * 32);                            \
  }

  float esum[4][4] = {};   // [m][reg]

  // diag (i==j) lives in half (d8>>2), slices [td0, td0+4), d8 = sr&7
  const int d8 = sr & 7;
  const bool diagh = ((d8 >> 2) == h);
  const int td0 = (d8 & 3) * 4;

#define STEP(BU, BP, T)                                                      \
  {                                                                          \
    const int t_ = (T);                                                      \
    if (t_ < 15) LOADB(BP, t_ + 1)                                           \
    f32x4 acc[4] = {};                                                       \
    _Pragma("unroll") for (int kk_ = 0; kk_ < 4; ++kk_)                      \
    _Pragma("unroll") for (int m_ = 0; m_ < 4; ++m_)                         \
        acc[m_] = __builtin_amdgcn_mfma_f32_16x16x32_fp8_fp8(af[kk_][m_],    \
                      BU[kk_], acc[m_], 0, 0, 0);                            \
    if (diagh && t_ >= td0 && t_ < td0 + 4) {                                \
      const int mt_ = t_ - td0;                                              \
      _Pragma("unroll") for (int m_ = 0; m_ < 4; ++m_)                       \
      _Pragma("unroll") for (int r_ = 0; r_ < 4; ++r_) {                     \
        float ex = fexp2(acc[m_][r_]);                                       \
        if (m_ == mt_ && (kg * 4 + r_) == fr) ex = 0.f;                      \
        esum[m_][r_] += ex;                                                  \
      }                                                                      \
    } else {                                                                 \
      _Pragma("unroll") for (int m_ = 0; m_ < 4; ++m_)                       \
      _Pragma("unroll") for (int r_ = 0; r_ < 4; ++r_)                       \
          esum[m_][r_] += fexp2(acc[m_][r_]);                                \
    }                                                                        \
  }

  LOADB(b0, 0)
  for (int tt = 0; tt < 8; ++tt) {
    STEP(b0, b1, 2 * tt)
    STEP(b1, b0, 2 * tt + 1)
  }
#undef STEP
#undef LOADB

  // ---- flush once: reduce over fr (16 cols) + plain stores ----
#pragma unroll
  for (int m = 0; m < 4; ++m)
#pragma unroll
    for (int reg = 0; reg < 4; ++reg) {
      float e = esum[m][reg];
      e += __shfl_xor(e, 1, 64); e += __shfl_xor(e, 2, 64);
      e += __shfl_xor(e, 4, 64); e += __shfl_xor(e, 8, 64);
      if (fr == 0)
        Pr[(((size_t)c * 2 + h) * 160 + sr) * 64 + m * 16 + kg * 4 + reg] = e;
    }
}

// Blocks [0,2560): wnum. The block's 4 pairs share class c = b/128: fold
// gp[c] once into LDS, then wave-per-pair dot.
// Blocks [2560,2600): Slog = log(sum of 40 Pr partials), coalesced.
__global__ __launch_bounds__(256) void k_ws(const float* __restrict__ Pr,
                                            const float* __restrict__ feat,
                                            const float* __restrict__ gp,
                                            float* __restrict__ Slog,
                                            float* __restrict__ wnum) {
  const int b = blockIdx.x;
  if (b < 2560) {
    __shared__ float part[2][128];
    __shared__ float gsh[128];
    const int tid = threadIdx.x;
    const int c = (b * 4) >> 9;                 // same class for all 4 pairs
    const int d = tid & 127, qh = tid >> 7;     // qh in {0,1}
    float s = 0.f;
#pragma unroll
    for (int q = 0; q < 8; ++q)
      s += gp[(c * 16 + qh * 8 + q) * 128 + d];
    part[qh][d] = s;
    __syncthreads();
    if (tid < 128) gsh[tid] = part[0][tid] + part[1][tid];
    __syncthreads();

    const int lane = tid & 63;
    const int p = b * 4 + (tid >> 6);           // pair c*512+i
    const int i = p & 511;
    float2 f = *(const float2*)(feat + (size_t)i * (NL * 128) + c * 128 + lane * 2);
    float2 gv = *(const float2*)(gsh + lane * 2);
    float v = f.x * gv.x + f.y * gv.y;
#pragma unroll
    for (int sh = 1; sh < 64; sh <<= 1) v += __shfl_xor(v, sh, 64);
    if (lane == 0) wnum[p] = (v - 1.f) * TEMP_INV;   // self term f.f==1 removed
  } else {
    int idx = (b - 2560) * 256 + threadIdx.x;   // [0, 10240)
    int c = idx >> 9, i = idx & 511;
    float s = 0.f;
#pragma unroll
    for (int l2 = 0; l2 < NL; ++l2) {
      const float* p2 = Pr + (((size_t)c * 2) * 160 + l2 * 8 + (i >> 6)) * 64 + (i & 63);
      s += p2[0] + p2[160 * 64];
    }
    Slog[idx] = logf(s);
  }
}

// Per-anchor combine + mean. One block, 512 threads.
__global__ __launch_bounds__(512) void k_final(const float* __restrict__ Slog,
                                               const float* __restrict__ wnum,
                                               const int* __restrict__ labels,
                                               float* __restrict__ out) {
  __shared__ float cnt[NL];
  __shared__ float red[8];
  const int i = threadIdx.x;
  if (i < NL) cnt[i] = 0.f;
  __syncthreads();
  int lab[NL];
#pragma unroll
  for (int cI = 0; cI < NL; ++cI) lab[cI] = labels[i * NL + cI];
#pragma unroll
  for (int cI = 0; cI < NL; ++cI)
    if (lab[cI]) atomicAdd(&cnt[cI], 1.f);
  __syncthreads();
  float avg = 0.f, acc = 0.f;
#pragma unroll
  for (int cI = 0; cI < NL; ++cI) {
    if (lab[cI]) {
      float wgt = cnt[cI] - 1.f;
      avg += wgt;
      acc += wnum[cI * NB + i] - wgt * Slog[cI * NB + i];
    }
  }
  float v = acc / (avg == 0.f ? 1.f : avg);
#pragma unroll
  for (int s = 1; s < 64; s <<= 1) v += __shfl_xor(v, s, 64);
  if ((i & 63) == 0) red[i >> 6] = v;
  __syncthreads();
  if (i == 0) {
    float tot = 0.f;
#pragma unroll
    for (int k = 0; k < 8; ++k) tot += red[k];
    out[0] = -(tot / (float)NB);
  }
}

extern "C" void kernel_launch(void* const* d_in, const int* in_sizes, int n_in,
                              void* d_out, int out_size, void* d_ws, size_t ws_size,
                              hipStream_t stream) {
  const float* feat = (const float*)d_in[0];
  const int* labels = (const int*)d_in[1];
  float* out = (float*)d_out;
  unsigned char* ws = (unsigned char*)d_ws;
  unsigned char* f8 = ws;                            // 1,310,720 B (fp8 linear)
  float* Pr = (float*)(ws + F8BYTES);                // 20*2*160*64 f32 = 1.6 MB
  float* gp = Pr + 20 * 2 * 160 * 64;                // 320*128 f32
  float* Slog = gp + 320 * 128;                      // 10240 f32
  float* wnum = Slog + NROW;                         // 10240 f32

  k_prep<<<960, 256, 0, stream>>>(feat, labels, f8, gp);
  dim3 grid(320, 20);
  k_gram<<<grid, 64, 0, stream>>>(f8, Pr);
  k_ws<<<2600, 256, 0, stream>>>(Pr, feat, gp, Slog, wnum);
  k_final<<<1, 512, 0, stream>>>(Slog, wnum, labels, out);
}

// Round 24
// 50.197 us; speedup vs baseline: 1.7189x; 1.7189x over previous
//
#include <hip/hip_runtime.h>
#include <hip/hip_fp8.h>

// NewSupConLoss: B=512, L=20, D=128. Full Gram N=10240, fused exp/rowsum.
// Round 24: R19 exactly, with the XOR swizzle widened from (a&7) to (a&15):
// read bank-spread goes 8 bank-pairs (4-way conflict, 1.64M conflict cycles)
// -> 16 bank-pairs (2-way = free). Single-variable change.

#define NB 512
#define NL 20
#define NROW (NB * NL)            // 10240
#define F8BYTES (NROW * 128)      // 1,310,720
#define SCALE 4.5398160f          // sqrt(log2(e)/0.07); dot feeds exp2 directly
#define TEMP_INV 14.285714285714286f

typedef float f32x4 __attribute__((ext_vector_type(4)));

static __device__ __forceinline__ unsigned char f2fp8(float x) {
  __hip_fp8_e4m3 q(x);
  return (unsigned char)q.__x;
}

static __device__ __forceinline__ float fexp2(float x) {
#if __has_builtin(__builtin_amdgcn_exp2f)
  return __builtin_amdgcn_exp2f(x);
#else
  return exp2f(x);
#endif
}

// Blocks [0,640): fp32 -> fp8 rows a=l*512+i, scaled, 8B-chunk XOR-swizzled
// with the FULL nibble (q ^ (a&15)). Blocks [640,960): gp partial g-sums.
__global__ __launch_bounds__(256) void k_prep(const float* __restrict__ feat,
                                              const int* __restrict__ labels,
                                              unsigned char* __restrict__ f8,
                                              float* __restrict__ gp) {
  const int b = blockIdx.x;
  if (b < 640) {
    int t = b * 256 + threadIdx.x;   // [0, 163840)
    int q = t & 15;                  // 8-elem chunk within row
    int a = t >> 4;                  // row 0..10239
    int l = a >> 9;
    int i = a & 511;
    const float* src = feat + (size_t)i * (NL * 128) + l * 128 + q * 8;
    float4 v0 = *(const float4*)src;
    float4 v1 = *(const float4*)(src + 4);
    unsigned long long u = 0;
    u |= (unsigned long long)f2fp8(v0.x * SCALE);
    u |= (unsigned long long)f2fp8(v0.y * SCALE) << 8;
    u |= (unsigned long long)f2fp8(v0.z * SCALE) << 16;
    u |= (unsigned long long)f2fp8(v0.w * SCALE) << 24;
    u |= (unsigned long long)f2fp8(v1.x * SCALE) << 32;
    u |= (unsigned long long)f2fp8(v1.y * SCALE) << 40;
    u |= (unsigned long long)f2fp8(v1.z * SCALE) << 48;
    u |= (unsigned long long)f2fp8(v1.w * SCALE) << 56;
    *(unsigned long long*)(f8 + (size_t)a * 128 + ((q ^ (a & 15)) << 3)) = u;
  } else {
    __shared__ float part[2][128];
    const int idx = b - 640;           // [0,320)
    const int c = idx >> 4, grp = idx & 15;
    const int d = threadIdx.x & 127, half = threadIdx.x >> 7;
    const int i0 = grp * 32 + half * 16;
    float s = 0.f;
#pragma unroll
    for (int k = 0; k < 16; ++k) {     // independent load pairs, latency-hidden
      int i = i0 + k;
      s += (float)labels[i * NL + c] * feat[(size_t)i * (NL * 128) + c * 128 + d];
    }
    part[half][d] = s;
    __syncthreads();
    if (half == 0) gp[(c * 16 + grp) * 128 + d] = part[0][d] + part[1][d];
  }
}

// Pr[c][h][sr][r] : partial row-sums of exp over 256 cols (class c, half h).
// Grid (320 = sr*2+h, 20 c), 64 threads (1 wave). Depth-1, 2x2KB LDS.
__global__ __launch_bounds__(64) void k_gram(const unsigned char* __restrict__ f8,
                                             float* __restrict__ Pr) {
  __shared__ unsigned char lds[4096];    // two wave-private 2KB slice buffers
  const int x = blockIdx.x;              // [0,320)
  const int h = x & 1, sr = x >> 1;      // col half, 64-row strip [sr*64,+64)
  const int c = blockIdx.y;              // class: cols [c*512 + h*256, +256)
  const int lane = threadIdx.x;          // 0..63
  const int fr = lane & 15, kg = lane >> 4;
  const int x8 = fr << 3;                // full-nibble row swizzle (row&15 == fr)

  // ---- persistent A fragments: 16 x long = 32 VGPR ----
  long af[4][4];   // [kk][m]
#pragma unroll
  for (int kk = 0; kk < 4; ++kk)
#pragma unroll
    for (int m = 0; m < 4; ++m)
      af[kk][m] = *(const long*)(f8 + (size_t)(sr * 64 + m * 16 + fr) * 128 +
                                 ((kk * 32 + kg * 8) ^ x8));

  const unsigned char* gB = f8 + ((size_t)c * 512 + h * 256) * 128 + lane * 16;
  auto stage = [&](int buf, int t) {     // slice t: 16 Gram-cols = 2KB
    const unsigned char* g = gB + t * 2048;
    unsigned char* lb = lds + buf * 2048 + lane * 16;
    __builtin_amdgcn_global_load_lds(
        (const __attribute__((address_space(1))) unsigned int*)g,
        (__attribute__((address_space(3))) unsigned int*)lb, 16, 0, 0);
    __builtin_amdgcn_global_load_lds(
        (const __attribute__((address_space(1))) unsigned int*)(g + 1024),
        (__attribute__((address_space(3))) unsigned int*)(lb + 1024), 16, 0, 0);
  };

  stage(0, 0);
  float esum[4][4] = {};   // [m][reg]

  // diag (i==j) lives in half (d8>>2), slices [td0, td0+4), d8 = sr&7
  const int d8 = sr & 7;
  const bool diagh = ((d8 >> 2) == h);
  const int td0 = (d8 & 3) * 4;

  for (int t = 0; t < 16; ++t) {
    asm volatile("" ::: "memory");   // keep stage below prior ds_reads
    if (t < 15) {
      stage((t + 1) & 1, t + 1);
      asm volatile("s_waitcnt vmcnt(2)" ::: "memory");   // slice t resident
    } else {
      asm volatile("s_waitcnt vmcnt(0)" ::: "memory");
    }

    const unsigned char* lb = lds + (t & 1) * 2048;
    f32x4 acc[4] = {};   // 64 rows x 16 cols
#pragma unroll
    for (int kk = 0; kk < 4; ++kk) {
      long bf = *(const long*)(lb + fr * 128 + ((kk * 32 + kg * 8) ^ x8));
#pragma unroll
      for (int m = 0; m < 4; ++m)
        acc[m] = __builtin_amdgcn_mfma_f32_16x16x32_fp8_fp8(af[kk][m], bf, acc[m], 0, 0, 0);
    }

    // ---- epilogue: exp + accumulate; mask only on the 4 diag slices ----
    if (diagh && t >= td0 && t < td0 + 4) {
      const int mt = t - td0;
#pragma unroll
      for (int m = 0; m < 4; ++m)
#pragma unroll
        for (int reg = 0; reg < 4; ++reg) {
          float ex = fexp2(acc[m][reg]);
          if (m == mt && (kg * 4 + reg) == fr) ex = 0.f;
          esum[m][reg] += ex;
        }
    } else {
#pragma unroll
      for (int m = 0; m < 4; ++m)
#pragma unroll
        for (int reg = 0; reg < 4; ++reg)
          esum[m][reg] += fexp2(acc[m][reg]);
    }
  }

  // ---- flush once: reduce over fr (16 cols) + plain stores ----
#pragma unroll
  for (int m = 0; m < 4; ++m)
#pragma unroll
    for (int reg = 0; reg < 4; ++reg) {
      float e = esum[m][reg];
      e += __shfl_xor(e, 1, 64); e += __shfl_xor(e, 2, 64);
      e += __shfl_xor(e, 4, 64); e += __shfl_xor(e, 8, 64);
      if (fr == 0)
        Pr[(((size_t)c * 2 + h) * 160 + sr) * 64 + m * 16 + kg * 4 + reg] = e;
    }
}

// Blocks [0,2560): wnum. The block's 4 pairs share class c = b/128: fold
// gp[c] once into LDS, then wave-per-pair dot.
// Blocks [2560,2600): Slog = log(sum of 40 Pr partials), coalesced.
__global__ __launch_bounds__(256) void k_ws(const float* __restrict__ Pr,
                                            const float* __restrict__ feat,
                                            const float* __restrict__ gp,
                                            float* __restrict__ Slog,
                                            float* __restrict__ wnum) {
  const int b = blockIdx.x;
  if (b < 2560) {
    __shared__ float part[2][128];
    __shared__ float gsh[128];
    const int tid = threadIdx.x;
    const int c = (b * 4) >> 9;                 // same class for all 4 pairs
    const int d = tid & 127, qh = tid >> 7;     // qh in {0,1}
    float s = 0.f;
#pragma unroll
    for (int q = 0; q < 8; ++q)
      s += gp[(c * 16 + qh * 8 + q) * 128 + d];
    part[qh][d] = s;
    __syncthreads();
    if (tid < 128) gsh[tid] = part[0][tid] + part[1][tid];
    __syncthreads();

    const int lane = tid & 63;
    const int p = b * 4 + (tid >> 6);           // pair c*512+i
    const int i = p & 511;
    float2 f = *(const float2*)(feat + (size_t)i * (NL * 128) + c * 128 + lane * 2);
    float2 gv = *(const float2*)(gsh + lane * 2);
    float v = f.x * gv.x + f.y * gv.y;
#pragma unroll
    for (int sh = 1; sh < 64; sh <<= 1) v += __shfl_xor(v, sh, 64);
    if (lane == 0) wnum[p] = (v - 1.f) * TEMP_INV;   // self term f.f==1 removed
  } else {
    int idx = (b - 2560) * 256 + threadIdx.x;   // [0, 10240)
    int c = idx >> 9, i = idx & 511;
    float s = 0.f;
#pragma unroll
    for (int l2 = 0; l2 < NL; ++l2) {
      const float* p2 = Pr + (((size_t)c * 2) * 160 + l2 * 8 + (i >> 6)) * 64 + (i & 63);
      s += p2[0] + p2[160 * 64];
    }
    Slog[idx] = logf(s);
  }
}

// Per-anchor combine + mean. One block, 512 threads.
__global__ __launch_bounds__(512) void k_final(const float* __restrict__ Slog,
                                               const float* __restrict__ wnum,
                                               const int* __restrict__ labels,
                                               float* __restrict__ out) {
  __shared__ float cnt[NL];
  __shared__ float red[8];
  const int i = threadIdx.x;
  if (i < NL) cnt[i] = 0.f;
  __syncthreads();
  int lab[NL];
#pragma unroll
  for (int cI = 0; cI < NL; ++cI) lab[cI] = labels[i * NL + cI];
#pragma unroll
  for (int cI = 0; cI < NL; ++cI)
    if (lab[cI]) atomicAdd(&cnt[cI], 1.f);
  __syncthreads();
  float avg = 0.f, acc = 0.f;
#pragma unroll
  for (int cI = 0; cI < NL; ++cI) {
    if (lab[cI]) {
      float wgt = cnt[cI] - 1.f;
      avg += wgt;
      acc += wnum[cI * NB + i] - wgt * Slog[cI * NB + i];
    }
  }
  float v = acc / (avg == 0.f ? 1.f : avg);
#pragma unroll
  for (int s = 1; s < 64; s <<= 1) v += __shfl_xor(v, s, 64);
  if ((i & 63) == 0) red[i >> 6] = v;
  __syncthreads();
  if (i == 0) {
    float tot = 0.f;
#pragma unroll
    for (int k = 0; k < 8; ++k) tot += red[k];
    out[0] = -(tot / (float)NB);
  }
}

extern "C" void kernel_launch(void* const* d_in, const int* in_sizes, int n_in,
                              void* d_out, int out_size, void* d_ws, size_t ws_size,
                              hipStream_t stream) {
  const float* feat = (const float*)d_in[0];
  const int* labels = (const int*)d_in[1];
  float* out = (float*)d_out;
  unsigned char* ws = (unsigned char*)d_ws;
  unsigned char* f8 = ws;                            // 1,310,720 B (fp8 swizzled)
  float* Pr = (float*)(ws + F8BYTES);                // 20*2*160*64 f32 = 1.6 MB
  float* gp = Pr + 20 * 2 * 160 * 64;                // 320*128 f32
  float* Slog = gp + 320 * 128;                      // 10240 f32
  float* wnum = Slog + NROW;                         // 10240 f32

  k_prep<<<960, 256, 0, stream>>>(feat, labels, f8, gp);
  dim3 grid(320, 20);
  k_gram<<<grid, 64, 0, stream>>>(f8, Pr);
  k_ws<<<2600, 256, 0, stream>>>(Pr, feat, gp, Slog, wnum);
  k_final<<<1, 512, 0, stream>>>(Slog, wnum, labels, out);
}